// Round 1
// baseline (194.614 us; speedup 1.0000x reference)
//
#include <hip/hip_runtime.h>
#include <stddef.h>

#define IMG_N 4096

// LDS layout (float offsets). Input tile region is reused (aliased) after
// stage 1 for conv outputs and reconstruction intermediates.
#define S_IN    0        // 80 x (stride 84) = 6720
#define S_LL1   6720     // 40 x (stride 42) = 1680
#define S_LH1   8400
#define S_HL1   10080
#define S_HH1   11760
#define S_LL2   13440    // 20 x (stride 22) = 440
#define S_LH2   13880
#define S_HL2   14320
#define S_HH2   14760
#define S_LL3   15200    // 10 x (stride 12) = 120
#define S_LH3   15320
#define S_HL3   15440
#define S_HH3   15560
#define S_TOTAL 15680    // 62,720 bytes

// Aliases into the dead S_IN region (input only read in stage 1):
#define S_HH1C  0        // 32 x (stride 36) = 1152
#define S_LL1P  1152     // 32 x (stride 36) = 1152
#define S_HH2C  2304     // 16 x (stride 20) = 320
#define S_LL2P  2624     // 16 x (stride 20) = 320
#define S_HH3C  2944     // 8  x (stride 12) = 96

__global__ __launch_bounds__(256) void haar_fused(
    const float* __restrict__ x,
    const float* __restrict__ w3, const float* __restrict__ b3,
    const float* __restrict__ w5, const float* __restrict__ b5,
    const float* __restrict__ w7, const float* __restrict__ b7,
    float* __restrict__ out)
{
    __shared__ __align__(16) float sm[S_TOTAL];
    const int tid = threadIdx.x;
    const int bx = blockIdx.x, by = blockIdx.y;
    const int R0 = by * 64, C0 = bx * 64;

    float* sIn = sm + S_IN;                 // stride 84, 80x80 valid
    float* LL1 = sm + S_LL1;                // stride 42, 40x40
    float* LH1 = sm + S_LH1;
    float* HL1 = sm + S_HL1;
    float* HH1 = sm + S_HH1;
    float* LL2 = sm + S_LL2;                // stride 22, 20x20
    float* LH2 = sm + S_LH2;
    float* HL2 = sm + S_HL2;
    float* HH2 = sm + S_HH2;
    float* LL3 = sm + S_LL3;                // stride 12, 10x10
    float* LH3 = sm + S_LH3;
    float* HL3 = sm + S_HL3;
    float* HH3 = sm + S_HH3;
    float* HH1C = sm + S_HH1C;              // stride 36, 32x32
    float* LL1P = sm + S_LL1P;              // stride 36, 32x32
    float* HH2C = sm + S_HH2C;              // stride 20, 16x16
    float* LL2P = sm + S_LL2P;              // stride 20, 16x16
    float* HH3C = sm + S_HH3C;              // stride 12, 8x8

    // ---- stage 0: load 80x80 input tile (halo 8), zero-padded outside image ----
    const bool interior = (by >= 1) && (by <= 62) && (bx >= 1) && (bx <= 62);
    if (interior) {
        const float* src = x + (size_t)(R0 - 8) * IMG_N + (C0 - 8);
        for (int idx = tid; idx < 1600; idx += 256) {          // 80 rows x 20 float4
            int r = idx / 20, c4 = (idx % 20) * 4;
            float4 v = *(const float4*)(src + (size_t)r * IMG_N + c4);
            *(float4*)(sIn + r * 84 + c4) = v;
        }
    } else {
        for (int idx = tid; idx < 6400; idx += 256) {
            int r = idx / 80, c = idx % 80;
            int gr = R0 - 8 + r, gc = C0 - 8 + c;
            float v = 0.0f;
            if (gr >= 0 && gr < IMG_N && gc >= 0 && gc < IMG_N)
                v = x[(size_t)gr * IMG_N + gc];
            sIn[r * 84 + c] = v;
        }
    }
    __syncthreads();

    // ---- stage 1: level-1 DWT: 80x80 -> 40x40 coeffs (2 coeff cols per item) ----
    for (int idx = tid; idx < 800; idx += 256) {               // 40 rows x 20 pairs
        int u = idx / 20, v2 = (idx % 20) * 2;                 // coeff cols v2, v2+1
        float4 t = *(const float4*)(sIn + (2 * u) * 84 + 2 * v2);
        float4 b = *(const float4*)(sIn + (2 * u + 1) * 84 + 2 * v2);
        float ll0 = (t.x + t.y + b.x + b.y) * 0.5f;
        float lh0 = (t.x + t.y - b.x - b.y) * 0.5f;
        float hl0 = (t.x - t.y + b.x - b.y) * 0.5f;
        float hh0 = (t.x - t.y - b.x + b.y) * 0.5f;
        float ll1 = (t.z + t.w + b.z + b.w) * 0.5f;
        float lh1 = (t.z + t.w - b.z - b.w) * 0.5f;
        float hl1 = (t.z - t.w + b.z - b.w) * 0.5f;
        float hh1 = (t.z - t.w - b.z + b.w) * 0.5f;
        int o = u * 42 + v2;
        *(float2*)(LL1 + o) = make_float2(ll0, ll1);
        *(float2*)(LH1 + o) = make_float2(lh0, lh1);
        *(float2*)(HL1 + o) = make_float2(hl0, hl1);
        *(float2*)(HH1 + o) = make_float2(hh0, hh1);
    }
    __syncthreads();

    // ---- stage 2: level-2 DWT on LL1: 40x40 -> 20x20 ----
    for (int idx = tid; idx < 200; idx += 256) {               // 20 rows x 10 pairs
        int u = idx / 10, v2 = (idx % 10) * 2;
        float4 t = *(const float4*)(LL1 + (2 * u) * 42 + 2 * v2);
        float4 b = *(const float4*)(LL1 + (2 * u + 1) * 42 + 2 * v2);
        float ll0 = (t.x + t.y + b.x + b.y) * 0.5f;
        float lh0 = (t.x + t.y - b.x - b.y) * 0.5f;
        float hl0 = (t.x - t.y + b.x - b.y) * 0.5f;
        float hh0 = (t.x - t.y - b.x + b.y) * 0.5f;
        float ll1 = (t.z + t.w + b.z + b.w) * 0.5f;
        float lh1 = (t.z + t.w - b.z - b.w) * 0.5f;
        float hl1 = (t.z - t.w + b.z - b.w) * 0.5f;
        float hh1 = (t.z - t.w - b.z + b.w) * 0.5f;
        int o = u * 22 + v2;
        *(float2*)(LL2 + o) = make_float2(ll0, ll1);
        *(float2*)(LH2 + o) = make_float2(lh0, lh1);
        *(float2*)(HL2 + o) = make_float2(hl0, hl1);
        *(float2*)(HH2 + o) = make_float2(hh0, hh1);
    }
    __syncthreads();

    // ---- stage 3: level-3 DWT on LL2: 20x20 -> 10x10 ----
    for (int idx = tid; idx < 50; idx += 256) {                // 10 rows x 5 pairs
        int u = idx / 5, v2 = (idx % 5) * 2;
        float4 t = *(const float4*)(LL2 + (2 * u) * 22 + 2 * v2);
        float4 b = *(const float4*)(LL2 + (2 * u + 1) * 22 + 2 * v2);
        float ll0 = (t.x + t.y + b.x + b.y) * 0.5f;
        float lh0 = (t.x + t.y - b.x - b.y) * 0.5f;
        float hl0 = (t.x - t.y + b.x - b.y) * 0.5f;
        float hh0 = (t.x - t.y - b.x + b.y) * 0.5f;
        float ll1 = (t.z + t.w + b.z + b.w) * 0.5f;
        float lh1 = (t.z + t.w - b.z - b.w) * 0.5f;
        float hl1 = (t.z - t.w + b.z - b.w) * 0.5f;
        float hh1 = (t.z - t.w - b.z + b.w) * 0.5f;
        int o = u * 12 + v2;
        *(float2*)(LL3 + o) = make_float2(ll0, ll1);
        *(float2*)(LH3 + o) = make_float2(lh0, lh1);
        *(float2*)(HL3 + o) = make_float2(hl0, hl1);
        *(float2*)(HH3 + o) = make_float2(hh0, hh1);
    }
    __syncthreads();

    // ---- stage 4a: conv7 on HH1 (in-tile 32x32; local coord = in-tile + 4) ----
    // Each thread computes a 1x4 strip with a sliding 10-wide register window.
    {
        const int i = tid >> 3;             // 0..31
        const int j0 = (tid & 7) << 2;      // 0,4,...,28
        const float bias = b7[0];
        float a0 = bias, a1 = bias, a2 = bias, a3 = bias;
        #pragma unroll
        for (int dy = 0; dy < 7; ++dy) {
            // local col = j + dx - 3 + 4 = j + dx + 1, j in [j0, j0+3], dx in [0,6]
            const float* row = HH1 + (i + dy + 1) * 42 + (j0 + 1);
            const float* wr = w7 + dy * 7;
            float r0 = row[0], r1 = row[1], r2 = row[2], r3 = row[3], r4 = row[4],
                  r5 = row[5], r6 = row[6], r7 = row[7], r8 = row[8], r9 = row[9];
            float q0 = wr[0], q1 = wr[1], q2 = wr[2], q3 = wr[3], q4 = wr[4],
                  q5 = wr[5], q6 = wr[6];
            a0 += q0*r0 + q1*r1 + q2*r2 + q3*r3 + q4*r4 + q5*r5 + q6*r6;
            a1 += q0*r1 + q1*r2 + q2*r3 + q3*r4 + q4*r5 + q5*r6 + q6*r7;
            a2 += q0*r2 + q1*r3 + q2*r4 + q3*r5 + q4*r6 + q5*r7 + q6*r8;
            a3 += q0*r3 + q1*r4 + q2*r5 + q3*r6 + q4*r7 + q5*r8 + q6*r9;
        }
        const int o = i * 36 + j0;
        HH1C[o] = a0; HH1C[o + 1] = a1; HH1C[o + 2] = a2; HH1C[o + 3] = a3;
    }
    // ---- stage 4b: conv5 on HH2 (in-tile 16x16; local coord = in-tile + 2) ----
    {
        const int i = tid >> 4;             // 0..15
        const int j = tid & 15;             // 0..15
        float acc = b5[0];
        #pragma unroll
        for (int dy = 0; dy < 5; ++dy) {
            const float* row = HH2 + (i + dy) * 22 + j;   // local col = j + dx
            const float* wr = w5 + dy * 5;
            acc += wr[0]*row[0] + wr[1]*row[1] + wr[2]*row[2] + wr[3]*row[3] + wr[4]*row[4];
        }
        HH2C[i * 20 + j] = acc;
    }
    // ---- stage 4c: conv3 on HH3 (in-tile 8x8; local coord = in-tile + 1) ----
    if (tid < 64) {
        const int i = tid >> 3, j = tid & 7;
        float acc = b3[0];
        #pragma unroll
        for (int dy = 0; dy < 3; ++dy) {
            const float* row = HH3 + (i + dy) * 12 + j;   // local col = j + dx
            const float* wr = w3 + dy * 3;
            acc += wr[0]*row[0] + wr[1]*row[1] + wr[2]*row[2];
        }
        HH3C[i * 12 + j] = acc;
    }
    __syncthreads();

    // ---- stage 5a: IDWT level 3 -> LL2' (in-tile 16x16) ----
    if (tid < 128) {                        // 16 rows x 8 col-pairs
        const int p = tid >> 3, c = tid & 7;
        const int r = p >> 1;
        const float sr = (p & 1) ? -1.0f : 1.0f;
        const int li = (r + 1) * 12 + (c + 1);
        float ll = LL3[li], lh = LH3[li], hl = HL3[li], hh = HH3C[r * 12 + c];
        float lo = ll + sr * lh, hi = hl + sr * hh;
        *(float2*)(LL2P + p * 20 + 2 * c) = make_float2((lo + hi) * 0.5f, (lo - hi) * 0.5f);
    }
    __syncthreads();

    // ---- stage 5b: IDWT level 2 -> LL1' (in-tile 32x32) ----
    for (int idx = tid; idx < 512; idx += 256) {               // 32 rows x 16 pairs
        const int p = idx >> 4, c = idx & 15;
        const int r = p >> 1;
        const float sr = (p & 1) ? -1.0f : 1.0f;
        const int li = (r + 2) * 22 + (c + 2);
        float ll = LL2P[r * 20 + c], lh = LH2[li], hl = HL2[li], hh = HH2C[r * 20 + c];
        float lo = ll + sr * lh, hi = hl + sr * hh;
        *(float2*)(LL1P + p * 36 + 2 * c) = make_float2((lo + hi) * 0.5f, (lo - hi) * 0.5f);
    }
    __syncthreads();

    // ---- stage 5c: IDWT level 1 -> out (64x64), coalesced float2 stores ----
    for (int idx = tid; idx < 2048; idx += 256) {              // 64 rows x 32 pairs
        const int p = idx >> 5, c = idx & 31;
        const int r = p >> 1;
        const float sr = (p & 1) ? -1.0f : 1.0f;
        const int li = (r + 4) * 42 + (c + 4);
        float ll = LL1P[r * 36 + c], lh = LH1[li], hl = HL1[li], hh = HH1C[r * 36 + c];
        float lo = ll + sr * lh, hi = hl + sr * hh;
        *(float2*)(out + (size_t)(R0 + p) * IMG_N + C0 + 2 * c)
            = make_float2((lo + hi) * 0.5f, (lo - hi) * 0.5f);
    }
}

extern "C" void kernel_launch(void* const* d_in, const int* in_sizes, int n_in,
                              void* d_out, int out_size, void* d_ws, size_t ws_size,
                              hipStream_t stream) {
    (void)in_sizes; (void)n_in; (void)out_size; (void)d_ws; (void)ws_size;
    const float* x  = (const float*)d_in[0];
    const float* w3 = (const float*)d_in[1];
    const float* b3 = (const float*)d_in[2];
    const float* w5 = (const float*)d_in[3];
    const float* b5 = (const float*)d_in[4];
    const float* w7 = (const float*)d_in[5];
    const float* b7 = (const float*)d_in[6];
    float* out = (float*)d_out;

    dim3 grid(IMG_N / 64, IMG_N / 64);     // 64x64 tiles of 64x64 output px
    dim3 block(256);
    haar_fused<<<grid, block, 0, stream>>>(x, w3, b3, w5, b5, w7, b7, out);
}

// Round 2
// 142.129 us; speedup vs baseline: 1.3693x; 1.3693x over previous
//
#include <hip/hip_runtime.h>
#include <stddef.h>

#define IMG_N 4096

// LDS layout (float offsets). 8,960 floats = 35,840 B -> 4 blocks/CU.
// Aliasing plan (all uses separated by __syncthreads):
//   LL1 slot  (dead after stage 2): HH1C + LL2P + HH3C
//   LL2 slot  (dead after stage 3): HH2C
//   HH1 slot  (dead after stage 4a): LL1P
#define S_LH1   0        // 40 x (stride 42) = 1680
#define S_HL1   1680
#define S_HH1   3360     // aliased by LL1P (32 x stride 36 = 1152) at stage 5b
#define S_LL1   5040     // 1680; aliased by HH1C(1152) / LL2P(320) / HH3C(96)
#define S_LL2   6720     // 20 x (stride 22) = 440; aliased by HH2C(320)
#define S_LH2   7160
#define S_HL2   7600
#define S_HH2   8040
#define S_LL3   8480     // 10 x (stride 12) = 120
#define S_LH3   8600
#define S_HL3   8720
#define S_HH3   8840
#define S_TOTAL 8960     // 35,840 bytes

#define S_HH1C  (S_LL1)           // 32 x (stride 36) = 1152
#define S_LL2P  (S_LL1 + 1152)    // 16 x (stride 20) = 320
#define S_HH3C  (S_LL1 + 1472)    // 8  x (stride 12) = 96
#define S_HH2C  (S_LL2)           // 16 x (stride 20) = 320
#define S_LL1P  (S_HH1)           // 32 x (stride 36) = 1152

__global__ __launch_bounds__(256) void haar_fused(
    const float* __restrict__ x,
    const float* __restrict__ w3, const float* __restrict__ b3,
    const float* __restrict__ w5, const float* __restrict__ b5,
    const float* __restrict__ w7, const float* __restrict__ b7,
    float* __restrict__ out)
{
    __shared__ __align__(16) float sm[S_TOTAL];
    const int tid = threadIdx.x;
    const int bx = blockIdx.x, by = blockIdx.y;
    const int R0 = by * 64, C0 = bx * 64;

    float* LH1 = sm + S_LH1;                // stride 42, 40x40
    float* HL1 = sm + S_HL1;
    float* HH1 = sm + S_HH1;
    float* LL1 = sm + S_LL1;
    float* LL2 = sm + S_LL2;                // stride 22, 20x20
    float* LH2 = sm + S_LH2;
    float* HL2 = sm + S_HL2;
    float* HH2 = sm + S_HH2;
    float* LL3 = sm + S_LL3;                // stride 12, 10x10
    float* LH3 = sm + S_LH3;
    float* HL3 = sm + S_HL3;
    float* HH3 = sm + S_HH3;
    float* HH1C = sm + S_HH1C;              // stride 36, 32x32
    float* LL1P = sm + S_LL1P;              // stride 36, 32x32
    float* HH2C = sm + S_HH2C;              // stride 20, 16x16
    float* LL2P = sm + S_LL2P;              // stride 20, 16x16
    float* HH3C = sm + S_HH3C;              // stride 12, 8x8

    // ---- stage 1: fused global load + level-1 DWT: 80x80 px -> 40x40 coeffs ----
    // 800 items = 40 coeff rows x 20 float4s (each float4 = 4 px = 2 coeff cols)
    const bool interior = (by >= 1) && (by <= 62) && (bx >= 1) && (bx <= 62);
    if (interior) {
        const float* src = x + (size_t)(R0 - 8) * IMG_N + (C0 - 8);
        for (int idx = tid; idx < 800; idx += 256) {
            int u = idx / 20, v2 = (idx % 20) * 2;             // coeff row, coeff col base
            const float* p = src + (size_t)(2 * u) * IMG_N + 2 * v2;
            float4 t = *(const float4*)(p);
            float4 b = *(const float4*)(p + IMG_N);
            int o = u * 42 + v2;
            *(float2*)(LL1 + o) = make_float2((t.x + t.y + b.x + b.y) * 0.5f,
                                              (t.z + t.w + b.z + b.w) * 0.5f);
            *(float2*)(LH1 + o) = make_float2((t.x + t.y - b.x - b.y) * 0.5f,
                                              (t.z + t.w - b.z - b.w) * 0.5f);
            *(float2*)(HL1 + o) = make_float2((t.x - t.y + b.x - b.y) * 0.5f,
                                              (t.z - t.w + b.z - b.w) * 0.5f);
            *(float2*)(HH1 + o) = make_float2((t.x - t.y - b.x + b.y) * 0.5f,
                                              (t.z - t.w - b.z + b.w) * 0.5f);
        }
    } else {
        for (int idx = tid; idx < 800; idx += 256) {
            int u = idx / 20, v2 = (idx % 20) * 2;
            int gr0 = R0 - 8 + 2 * u, gr1 = gr0 + 1;
            int gc = C0 - 8 + 2 * v2;
            bool r0v = (gr0 >= 0 && gr0 < IMG_N), r1v = (gr1 >= 0 && gr1 < IMG_N);
            float tv[4], bv[4];
            #pragma unroll
            for (int k = 0; k < 4; ++k) {
                int g = gc + k;
                bool cv = (g >= 0 && g < IMG_N);
                tv[k] = (r0v && cv) ? x[(size_t)gr0 * IMG_N + g] : 0.0f;
                bv[k] = (r1v && cv) ? x[(size_t)gr1 * IMG_N + g] : 0.0f;
            }
            int o = u * 42 + v2;
            *(float2*)(LL1 + o) = make_float2((tv[0] + tv[1] + bv[0] + bv[1]) * 0.5f,
                                              (tv[2] + tv[3] + bv[2] + bv[3]) * 0.5f);
            *(float2*)(LH1 + o) = make_float2((tv[0] + tv[1] - bv[0] - bv[1]) * 0.5f,
                                              (tv[2] + tv[3] - bv[2] - bv[3]) * 0.5f);
            *(float2*)(HL1 + o) = make_float2((tv[0] - tv[1] + bv[0] - bv[1]) * 0.5f,
                                              (tv[2] - tv[3] + bv[2] - bv[3]) * 0.5f);
            *(float2*)(HH1 + o) = make_float2((tv[0] - tv[1] - bv[0] + bv[1]) * 0.5f,
                                              (tv[2] - tv[3] - bv[2] + bv[3]) * 0.5f);
        }
    }
    __syncthreads();

    // ---- stage 2: level-2 DWT on LL1: 40x40 -> 20x20 ----
    for (int idx = tid; idx < 200; idx += 256) {               // 20 rows x 10 pairs
        int u = idx / 10, v2 = (idx % 10) * 2;
        float4 t = *(const float4*)(LL1 + (2 * u) * 42 + 2 * v2);
        float4 b = *(const float4*)(LL1 + (2 * u + 1) * 42 + 2 * v2);
        int o = u * 22 + v2;
        *(float2*)(LL2 + o) = make_float2((t.x + t.y + b.x + b.y) * 0.5f,
                                          (t.z + t.w + b.z + b.w) * 0.5f);
        *(float2*)(LH2 + o) = make_float2((t.x + t.y - b.x - b.y) * 0.5f,
                                          (t.z + t.w - b.z - b.w) * 0.5f);
        *(float2*)(HL2 + o) = make_float2((t.x - t.y + b.x - b.y) * 0.5f,
                                          (t.z - t.w + b.z - b.w) * 0.5f);
        *(float2*)(HH2 + o) = make_float2((t.x - t.y - b.x + b.y) * 0.5f,
                                          (t.z - t.w - b.z + b.w) * 0.5f);
    }
    __syncthreads();

    // ---- stage 3: level-3 DWT on LL2: 20x20 -> 10x10 ----
    for (int idx = tid; idx < 50; idx += 256) {                // 10 rows x 5 pairs
        int u = idx / 5, v2 = (idx % 5) * 2;
        float4 t = *(const float4*)(LL2 + (2 * u) * 22 + 2 * v2);
        float4 b = *(const float4*)(LL2 + (2 * u + 1) * 22 + 2 * v2);
        int o = u * 12 + v2;
        *(float2*)(LL3 + o) = make_float2((t.x + t.y + b.x + b.y) * 0.5f,
                                          (t.z + t.w + b.z + b.w) * 0.5f);
        *(float2*)(LH3 + o) = make_float2((t.x + t.y - b.x - b.y) * 0.5f,
                                          (t.z + t.w - b.z - b.w) * 0.5f);
        *(float2*)(HL3 + o) = make_float2((t.x - t.y + b.x - b.y) * 0.5f,
                                          (t.z - t.w + b.z - b.w) * 0.5f);
        *(float2*)(HH3 + o) = make_float2((t.x - t.y - b.x + b.y) * 0.5f,
                                          (t.z - t.w - b.z + b.w) * 0.5f);
    }
    __syncthreads();

    // ---- stage 4a: conv7 on HH1 (in-tile 32x32; local = in-tile + 4) ----
    {
        const int i = tid >> 3;             // 0..31
        const int j0 = (tid & 7) << 2;      // 0,4,...,28
        const float bias = b7[0];
        float a0 = bias, a1 = bias, a2 = bias, a3 = bias;
        #pragma unroll
        for (int dy = 0; dy < 7; ++dy) {
            const float* row = HH1 + (i + dy + 1) * 42 + (j0 + 1);
            const float* wr = w7 + dy * 7;
            float r0 = row[0], r1 = row[1], r2 = row[2], r3 = row[3], r4 = row[4],
                  r5 = row[5], r6 = row[6], r7 = row[7], r8 = row[8], r9 = row[9];
            float q0 = wr[0], q1 = wr[1], q2 = wr[2], q3 = wr[3], q4 = wr[4],
                  q5 = wr[5], q6 = wr[6];
            a0 += q0*r0 + q1*r1 + q2*r2 + q3*r3 + q4*r4 + q5*r5 + q6*r6;
            a1 += q0*r1 + q1*r2 + q2*r3 + q3*r4 + q4*r5 + q5*r6 + q6*r7;
            a2 += q0*r2 + q1*r3 + q2*r4 + q3*r5 + q4*r6 + q5*r7 + q6*r8;
            a3 += q0*r3 + q1*r4 + q2*r5 + q3*r6 + q4*r7 + q5*r8 + q6*r9;
        }
        const int o = i * 36 + j0;
        HH1C[o] = a0; HH1C[o + 1] = a1; HH1C[o + 2] = a2; HH1C[o + 3] = a3;
    }
    // ---- stage 4b: conv5 on HH2 (in-tile 16x16; local = in-tile + 2) ----
    {
        const int i = tid >> 4, j = tid & 15;
        float acc = b5[0];
        #pragma unroll
        for (int dy = 0; dy < 5; ++dy) {
            const float* row = HH2 + (i + dy) * 22 + j;
            const float* wr = w5 + dy * 5;
            acc += wr[0]*row[0] + wr[1]*row[1] + wr[2]*row[2] + wr[3]*row[3] + wr[4]*row[4];
        }
        HH2C[i * 20 + j] = acc;
    }
    // ---- stage 4c: conv3 on HH3 (in-tile 8x8; local = in-tile + 1) ----
    if (tid < 64) {
        const int i = tid >> 3, j = tid & 7;
        float acc = b3[0];
        #pragma unroll
        for (int dy = 0; dy < 3; ++dy) {
            const float* row = HH3 + (i + dy) * 12 + j;
            const float* wr = w3 + dy * 3;
            acc += wr[0]*row[0] + wr[1]*row[1] + wr[2]*row[2];
        }
        HH3C[i * 12 + j] = acc;
    }
    __syncthreads();

    // ---- stage 5a: IDWT level 3 -> LL2' (in-tile 16x16) ----
    if (tid < 128) {                        // 16 out rows x 8 col-pairs
        const int p = tid >> 3, c = tid & 7;
        const int r = p >> 1;
        const float sr = (p & 1) ? -1.0f : 1.0f;
        const int li = (r + 1) * 12 + (c + 1);
        float lo = LL3[li] + sr * LH3[li];
        float hi = HL3[li] + sr * HH3C[r * 12 + c];
        *(float2*)(LL2P + p * 20 + 2 * c) = make_float2((lo + hi) * 0.5f, (lo - hi) * 0.5f);
    }
    __syncthreads();

    // ---- stage 5b: IDWT level 2 -> LL1' (in-tile 32x32) ----
    for (int idx = tid; idx < 512; idx += 256) {               // 32 out rows x 16 pairs
        const int p = idx >> 4, c = idx & 15;
        const int r = p >> 1;
        const float sr = (p & 1) ? -1.0f : 1.0f;
        const int li = (r + 2) * 22 + (c + 2);
        float lo = LL2P[r * 20 + c] + sr * LH2[li];
        float hi = HL2[li] + sr * HH2C[r * 20 + c];
        *(float2*)(LL1P + p * 36 + 2 * c) = make_float2((lo + hi) * 0.5f, (lo - hi) * 0.5f);
    }
    __syncthreads();

    // ---- stage 5c: IDWT level 1 -> out (64x64), float4 stores ----
    for (int idx = tid; idx < 1024; idx += 256) {              // 64 rows x 16 float4
        const int p = idx >> 4;             // out row
        const int c2 = (idx & 15) * 2;      // coeff col base (covers c2, c2+1)
        const int r = p >> 1;
        const float sr = (p & 1) ? -1.0f : 1.0f;
        const int li = (r + 4) * 42 + (c2 + 4);
        const int ci = r * 36 + c2;
        float lo0 = LL1P[ci]     + sr * LH1[li];
        float hi0 = HL1[li]      + sr * HH1C[ci];
        float lo1 = LL1P[ci + 1] + sr * LH1[li + 1];
        float hi1 = HL1[li + 1]  + sr * HH1C[ci + 1];
        float4 o = make_float4((lo0 + hi0) * 0.5f, (lo0 - hi0) * 0.5f,
                               (lo1 + hi1) * 0.5f, (lo1 - hi1) * 0.5f);
        *(float4*)(out + (size_t)(R0 + p) * IMG_N + C0 + 2 * c2) = o;
    }
}

extern "C" void kernel_launch(void* const* d_in, const int* in_sizes, int n_in,
                              void* d_out, int out_size, void* d_ws, size_t ws_size,
                              hipStream_t stream) {
    (void)in_sizes; (void)n_in; (void)out_size; (void)d_ws; (void)ws_size;
    const float* x  = (const float*)d_in[0];
    const float* w3 = (const float*)d_in[1];
    const float* b3 = (const float*)d_in[2];
    const float* w5 = (const float*)d_in[3];
    const float* b5 = (const float*)d_in[4];
    const float* w7 = (const float*)d_in[5];
    const float* b7 = (const float*)d_in[6];
    float* out = (float*)d_out;

    dim3 grid(IMG_N / 64, IMG_N / 64);     // 64x64 tiles of 64x64 output px
    dim3 block(256);
    haar_fused<<<grid, block, 0, stream>>>(x, w3, b3, w5, b5, w7, b7, out);
}